// Round 5
// baseline (5719.377 us; speedup 1.0000x reference)
//
#include <hip/hip_runtime.h>
#include <math.h>

// Problem constants (MSDeformMatchV2HeaderAttn)
#define BB 2
#define LQ 1024
#define DM 256
#define NH 8
#define DH 32
#define NL 4
#define HWsp 1024   // 32*32
#define LIN 4096
#define K9 36
#define NGRP (BB * NH * NL * LQ)  // 65536 (n,h,l,q) groups

// ---------------------------------------------------------------------------
// Kernel 1 (v4): fused corr + stable top-4, k-split x2 for occupancy.
// corr[q][k] = dot(Q[q], V[k]) over d=32, fp32, ascending-d association.
// Stable top-4 == top-4 under (value desc, index asc).
// SPLIT=2: grid (32, 4, 16): blockIdx.x = qc*2+half, each block scans 512 k,
//          writes partial sorted (val,idx) 4-lists; merge kernel combines.
// SPLIT=1: grid (16, 4, 16), full scan, writes idx_buf directly.
// ---------------------------------------------------------------------------
#define INSERT4Q(qi, val, index)                                              \
  {                                                                           \
    const float v_ = (val);                                                   \
    const int ix_ = (index);                                                  \
    if (v_ > v3[qi]) {                                                        \
      if (v_ > v1[qi]) {                                                      \
        if (v_ > v0[qi]) {                                                    \
          v3[qi] = v2[qi]; i3[qi] = i2[qi]; v2[qi] = v1[qi]; i2[qi] = i1[qi]; \
          v1[qi] = v0[qi]; i1[qi] = i0[qi]; v0[qi] = v_; i0[qi] = ix_;        \
        } else {                                                              \
          v3[qi] = v2[qi]; i3[qi] = i2[qi]; v2[qi] = v1[qi]; i2[qi] = i1[qi]; \
          v1[qi] = v_; i1[qi] = ix_;                                          \
        }                                                                     \
      } else {                                                                \
        if (v_ > v2[qi]) {                                                    \
          v3[qi] = v2[qi]; i3[qi] = i2[qi]; v2[qi] = v_; i2[qi] = ix_;        \
        } else {                                                              \
          v3[qi] = v_; i3[qi] = ix_;                                          \
        }                                                                     \
      }                                                                       \
    }                                                                         \
  }

// a := lexmax(a, b)  under (value desc, index asc)
#define LMAX(av, ai, bv, bi)                                        \
  {                                                                 \
    const bool g_ = ((av) > (bv)) || ((av) == (bv) && (ai) < (bi)); \
    if (!g_) { (av) = (bv); (ai) = (bi); }                          \
  }
// compare-exchange: order (a,b) so a >=lex b
#define CEX(av, ai, bv, bi)                                         \
  {                                                                 \
    const bool g_ = ((av) > (bv)) || ((av) == (bv) && (ai) < (bi)); \
    const float tv_ = g_ ? (av) : (bv);                             \
    const int ti_ = g_ ? (ai) : (bi);                               \
    (bv) = g_ ? (bv) : (av); (bi) = g_ ? (bi) : (ai);               \
    (av) = tv_; (ai) = ti_;                                         \
  }

template <int SPLIT>
__global__ __launch_bounds__(256, 4) void corr_topk_kernel(
    const float* __restrict__ query, const float* __restrict__ value,
    int* __restrict__ idx_out, float4* __restrict__ pval,
    int4* __restrict__ pidx) {
  __shared__ float qT[32][68];  // [d][q_local], pad 68 (16B-aligned rows)
  __shared__ float vT[32][68];  // [d][k_local]

  const int tid = threadIdx.x;
  const int nh = blockIdx.z;  // n*8+h
  const int n = nh >> 3, h = nh & 7;
  const int l = blockIdx.y;
  const int qc = (SPLIT == 2) ? (blockIdx.x >> 1) : blockIdx.x;
  const int half = (SPLIT == 2) ? (blockIdx.x & 1) : 0;
  const int kc0 = (SPLIT == 2) ? (half << 3) : 0;
  const int kc1 = (SPLIT == 2) ? (kc0 + 8) : 16;
  const int qb = qc << 6;                // 64 queries per block
  const int d = tid & 31, r = tid >> 5;  // loader mapping
  const int tq = tid >> 4, tk = tid & 15;

  // Stage Q^T once: qT[d][q] = query[n][qb+q][h*32+d]
  {
    const float* qg = query + (size_t)(n * LQ + qb) * DM + h * DH + d;
    #pragma unroll
    for (int i = 0; i < 8; ++i) qT[d][r + (i << 3)] = qg[(size_t)(r + (i << 3)) * DM];
  }

  // per-thread top-4 state for 4 q-rows (sorted desc, lexicographic)
  float v0[4], v1[4], v2[4], v3[4];
  int i0[4], i1[4], i2[4], i3[4];
  #pragma unroll
  for (int qi = 0; qi < 4; ++qi) {
    v0[qi] = v1[qi] = v2[qi] = v3[qi] = -INFINITY;
    i0[qi] = i1[qi] = i2[qi] = i3[qi] = 0;
  }

  const float* vgbase = value + (size_t)(n * LIN + l * HWsp) * DM + h * DH + d;

  for (int kc = kc0; kc < kc1; ++kc) {
    // Stage V^T chunk: vT[d][kk] = value row (kc*64+kk)
    {
      const float* vg = vgbase + (size_t)(kc << 6) * DM;
      #pragma unroll
      for (int i = 0; i < 8; ++i) vT[d][r + (i << 3)] = vg[(size_t)(r + (i << 3)) * DM];
    }
    __syncthreads();  // vT ready

    // 4x4 register tile: q = qb + 4*tq+qi, k = kc*64 + 4*tk+kj
    float a00 = 0.f, a01 = 0.f, a02 = 0.f, a03 = 0.f;
    float a10 = 0.f, a11 = 0.f, a12 = 0.f, a13 = 0.f;
    float a20 = 0.f, a21 = 0.f, a22 = 0.f, a23 = 0.f;
    float a30 = 0.f, a31 = 0.f, a32 = 0.f, a33 = 0.f;
    #pragma unroll
    for (int d0 = 0; d0 < 32; ++d0) {
      const float4 qv = *(const float4*)&qT[d0][tq << 2];
      const float4 vv = *(const float4*)&vT[d0][tk << 2];
      a00 = fmaf(qv.x, vv.x, a00); a01 = fmaf(qv.x, vv.y, a01);
      a02 = fmaf(qv.x, vv.z, a02); a03 = fmaf(qv.x, vv.w, a03);
      a10 = fmaf(qv.y, vv.x, a10); a11 = fmaf(qv.y, vv.y, a11);
      a12 = fmaf(qv.y, vv.z, a12); a13 = fmaf(qv.y, vv.w, a13);
      a20 = fmaf(qv.z, vv.x, a20); a21 = fmaf(qv.z, vv.y, a21);
      a22 = fmaf(qv.z, vv.z, a22); a23 = fmaf(qv.z, vv.w, a23);
      a30 = fmaf(qv.w, vv.x, a30); a31 = fmaf(qv.w, vv.y, a31);
      a32 = fmaf(qv.w, vv.z, a32); a33 = fmaf(qv.w, vv.w, a33);
    }

    // local stable top-4 update (ascending k within this thread's columns)
    {
      const int kb = (kc << 6) + (tk << 2);
      INSERT4Q(0, a00, kb + 0); INSERT4Q(0, a01, kb + 1);
      INSERT4Q(0, a02, kb + 2); INSERT4Q(0, a03, kb + 3);
      INSERT4Q(1, a10, kb + 0); INSERT4Q(1, a11, kb + 1);
      INSERT4Q(1, a12, kb + 2); INSERT4Q(1, a13, kb + 3);
      INSERT4Q(2, a20, kb + 0); INSERT4Q(2, a21, kb + 1);
      INSERT4Q(2, a22, kb + 2); INSERT4Q(2, a23, kb + 3);
      INSERT4Q(3, a30, kb + 0); INSERT4Q(3, a31, kb + 1);
      INSERT4Q(3, a32, kb + 2); INSERT4Q(3, a33, kb + 3);
    }
    __syncthreads();  // all reads of vT done before next stage
  }

  // Butterfly lexicographic merge across the 16 tk-threads (validated R2/R3)
  #pragma unroll
  for (int m = 1; m < 16; m <<= 1) {
    #pragma unroll
    for (int qi = 0; qi < 4; ++qi) {
      const float b0 = __shfl_xor(v0[qi], m);
      const float b1 = __shfl_xor(v1[qi], m);
      const float b2 = __shfl_xor(v2[qi], m);
      const float b3 = __shfl_xor(v3[qi], m);
      const int j0 = __shfl_xor(i0[qi], m);
      const int j1 = __shfl_xor(i1[qi], m);
      const int j2 = __shfl_xor(i2[qi], m);
      const int j3 = __shfl_xor(i3[qi], m);
      LMAX(v0[qi], i0[qi], b3, j3);
      LMAX(v1[qi], i1[qi], b2, j2);
      LMAX(v2[qi], i2[qi], b1, j1);
      LMAX(v3[qi], i3[qi], b0, j0);
      CEX(v0[qi], i0[qi], v2[qi], i2[qi]);
      CEX(v1[qi], i1[qi], v3[qi], i3[qi]);
      CEX(v0[qi], i0[qi], v1[qi], i1[qi]);
      CEX(v2[qi], i2[qi], v3[qi], i3[qi]);
    }
  }

  if (tk == 0) {
    #pragma unroll
    for (int qi = 0; qi < 4; ++qi) {
      const int q = qb + tq * 4 + qi;
      const size_t g = (((size_t)nh * NL + l) << 10) + q;  // group index
      if (SPLIT == 2) {
        pval[g * 2 + half] = make_float4(v0[qi], v1[qi], v2[qi], v3[qi]);
        pidx[g * 2 + half] = make_int4(i0[qi], i1[qi], i2[qi], i3[qi]);
      } else {
        ((int4*)idx_out)[g] = make_int4(i0[qi], i1[qi], i2[qi], i3[qi]);
      }
    }
  }
}

// ---------------------------------------------------------------------------
// Kernel 1b: merge the two k-half partial top-4 lists per group.
// ---------------------------------------------------------------------------
__global__ __launch_bounds__(256) void merge_topk_kernel(
    const float4* __restrict__ pval, const int4* __restrict__ pidx,
    int* __restrict__ idx_out) {
  const int t = blockIdx.x * 256 + threadIdx.x;  // < NGRP
  const float4 av = pval[t * 2 + 0];
  const int4 ai = pidx[t * 2 + 0];
  const float4 bv = pval[t * 2 + 1];
  const int4 bi = pidx[t * 2 + 1];
  float w0 = av.x, w1 = av.y, w2 = av.z, w3 = av.w;
  int m0 = ai.x, m1 = ai.y, m2 = ai.z, m3 = ai.w;
  LMAX(w0, m0, bv.w, bi.w);
  LMAX(w1, m1, bv.z, bi.z);
  LMAX(w2, m2, bv.y, bi.y);
  LMAX(w3, m3, bv.x, bi.x);
  CEX(w0, m0, w2, m2);
  CEX(w1, m1, w3, m3);
  CEX(w0, m0, w1, m1);
  CEX(w2, m2, w3, m3);
  ((int4*)idx_out)[t] = make_int4(m0, m1, m2, m3);
}

// ---------------------------------------------------------------------------
// Kernel 2: loc output. res=clip(idx+delta,0,961); loc=(res>>5, res&31)/32.
// One thread per (n,q,h,l,k9) pair -> writes float2. Exact in fp32.
// ---------------------------------------------------------------------------
__global__ __launch_bounds__(256) void loc_kernel(const int* __restrict__ idx_buf,
                                                  float* __restrict__ loc) {
  const int t = blockIdx.x * 256 + threadIdx.x;  // < 2359296
  const int k = t % 36;
  int rest = t / 36;
  const int l = rest & 3; rest >>= 2;
  const int h = rest & 7; rest >>= 3;
  const int q = rest & 1023;
  const int n = rest >> 10;
  const int p = k & 3, dd = k >> 2;  // delta-major: k = dd*4 + p
  const int idx = idx_buf[(((((n << 3) + h) * NL + l) << 10) + q) * 4 + p];
  const int delta = ((dd / 3) - 1) * 32 + (dd % 3) - 1;  // {-33,-32,-31,-1,0,1,31,32,33}
  int res = idx + delta;
  res = min(max(res, 0), 961);
  const int W = res >> 5, H = res & 31;
  ((float2*)loc)[t] = make_float2((float)W * 0.03125f, (float)H * 0.03125f);
}

// ---------------------------------------------------------------------------
// Kernel 3: gather+average. All bilinear weights are exactly 0.25; corners of
// cell (H=res&31, W=res>>5) are rows {g, g-1, g-32, g-33}, g = H*32+W, gated
// by W>=1 / H>=1 (gates applied as 0/1 weights, addresses clamped to >=0).
// Block = (n,q); thread = (l, h, d4): wave = one level; float4 per lane.
// ---------------------------------------------------------------------------
__global__ __launch_bounds__(256) void gather_kernel(
    const float* __restrict__ value, const int* __restrict__ idx_buf,
    float* __restrict__ acc_out) {
  __shared__ float red[NL][DM];
  const int nq = blockIdx.x;  // n*1024+q
  const int n = nq >> 10, q = nq & 1023;
  const int tid = threadIdx.x;
  const int l = tid >> 6;          // wave index = level
  const int h = (tid >> 3) & 7;
  const int d4 = tid & 7;          // float4 lane within the 32-float head dim

  const int4 id4 =
      ((const int4*)idx_buf)[((((size_t)((n << 3) + h)) * NL + l) << 10) + q];

  const float4* vb4 =
      (const float4*)(value + (size_t)(n * LIN + l * HWsp) * DM + h * DH) + d4;

  float4 a = make_float4(0.f, 0.f, 0.f, 0.f);
  #pragma unroll
  for (int p = 0; p < 4; ++p) {
    const int idx = (p == 0) ? id4.x : (p == 1) ? id4.y : (p == 2) ? id4.z : id4.w;
    #pragma unroll
    for (int dy = -1; dy <= 1; ++dy) {
      #pragma unroll
      for (int dx = -1; dx <= 1; ++dx) {
        int res = idx + dy * 32 + dx;
        res = min(max(res, 0), 961);
        const int W = res >> 5, H = res & 31;
        const int g = (H << 5) + W;
        const float wW = (W >= 1) ? 1.f : 0.f;
        const float wH = (H >= 1) ? 1.f : 0.f;
        const float wB = wW * wH;
        const float4 c0 = vb4[(size_t)g * 64];
        const float4 c1 = vb4[(size_t)max(g - 1, 0) * 64];
        const float4 c2 = vb4[(size_t)max(g - 32, 0) * 64];
        const float4 c3 = vb4[(size_t)max(g - 33, 0) * 64];
        a.x += c0.x + wW * c1.x + wH * c2.x + wB * c3.x;
        a.y += c0.y + wW * c1.y + wH * c2.y + wB * c3.y;
        a.z += c0.z + wW * c1.z + wH * c2.z + wB * c3.z;
        a.w += c0.w + wW * c1.w + wH * c2.w + wB * c3.w;
      }
    }
  }

  const int col = h * DH + d4 * 4;
  red[l][col + 0] = a.x;
  red[l][col + 1] = a.y;
  red[l][col + 2] = a.z;
  red[l][col + 3] = a.w;
  __syncthreads();
  const float s = red[0][tid] + red[1][tid] + red[2][tid] + red[3][tid];
  acc_out[(size_t)nq * DM + tid] = s * (1.0f / 576.0f);
}

// ---------------------------------------------------------------------------
// Kernel 4: out = acc @ W^T + b.  256 blocks x 256 threads, 8 q-rows/block.
// ---------------------------------------------------------------------------
__global__ __launch_bounds__(256) void proj_kernel(
    const float* __restrict__ acc_in, const float* __restrict__ W,
    const float* __restrict__ bias, float* __restrict__ out) {
  __shared__ float la[8][256];
  const int qb = blockIdx.x << 3;
  const int tid = threadIdx.x;
  for (int i = tid; i < 8 * 256; i += 256)
    la[i >> 8][i & 255] = acc_in[((size_t)qb << 8) + i];
  __syncthreads();
  const float* wrow = W + (size_t)tid * 256;
  float s0 = 0.f, s1 = 0.f, s2 = 0.f, s3 = 0.f, s4 = 0.f, s5 = 0.f, s6 = 0.f, s7 = 0.f;
  for (int c0 = 0; c0 < 256; c0 += 4) {
    const float4 wv = *(const float4*)(wrow + c0);
    #define PROJ_STEP(qi, sreg)                                   \
      {                                                           \
        const float4 av = *(const float4*)&la[qi][c0];            \
        sreg = fmaf(wv.x, av.x, sreg);                            \
        sreg = fmaf(wv.y, av.y, sreg);                            \
        sreg = fmaf(wv.z, av.z, sreg);                            \
        sreg = fmaf(wv.w, av.w, sreg);                            \
      }
    PROJ_STEP(0, s0) PROJ_STEP(1, s1) PROJ_STEP(2, s2) PROJ_STEP(3, s3)
    PROJ_STEP(4, s4) PROJ_STEP(5, s5) PROJ_STEP(6, s6) PROJ_STEP(7, s7)
    #undef PROJ_STEP
  }
  const float bj = bias[tid];
  out[(size_t)(qb + 0) * 256 + tid] = s0 + bj;
  out[(size_t)(qb + 1) * 256 + tid] = s1 + bj;
  out[(size_t)(qb + 2) * 256 + tid] = s2 + bj;
  out[(size_t)(qb + 3) * 256 + tid] = s3 + bj;
  out[(size_t)(qb + 4) * 256 + tid] = s4 + bj;
  out[(size_t)(qb + 5) * 256 + tid] = s5 + bj;
  out[(size_t)(qb + 6) * 256 + tid] = s6 + bj;
  out[(size_t)(qb + 7) * 256 + tid] = s7 + bj;
}

// ---------------------------------------------------------------------------
extern "C" void kernel_launch(void* const* d_in, const int* in_sizes, int n_in,
                              void* d_out, int out_size, void* d_ws, size_t ws_size,
                              hipStream_t stream) {
  (void)in_sizes; (void)n_in; (void)out_size;
  const float* query = (const float*)d_in[0];
  const float* value = (const float*)d_in[2];
  const float* opw = (const float*)d_in[5];
  const float* opb = (const float*)d_in[6];

  float* out = (float*)d_out;               // [2,1024,256]
  float* loc = out + (size_t)BB * LQ * DM;  // [2,1024,8,4,36,2]

  const size_t PART = (size_t)NGRP * 2 * 16;  // 2 MB each (pval, pidx)
  const size_t IDXB = (size_t)NGRP * 4 * sizeof(int);  // 1 MB
  const size_t ACCB = (size_t)BB * LQ * DM * sizeof(float);  // 2 MB

  if (ws_size >= 2 * PART + IDXB + ACCB) {
    float4* pval = (float4*)d_ws;
    int4* pidx = (int4*)((char*)d_ws + PART);
    int* idx_buf = (int*)((char*)d_ws + 2 * PART);
    float* acc_buf = (float*)((char*)d_ws + 2 * PART + IDXB);

    corr_topk_kernel<2><<<dim3(32, NL, BB * NH), 256, 0, stream>>>(
        query, value, idx_buf, pval, pidx);
    merge_topk_kernel<<<dim3(NGRP / 256), 256, 0, stream>>>(pval, pidx, idx_buf);
    loc_kernel<<<dim3((BB * LQ * NH * NL * K9) / 256), 256, 0, stream>>>(idx_buf, loc);
    gather_kernel<<<dim3(BB * LQ), 256, 0, stream>>>(value, idx_buf, acc_buf);
    proj_kernel<<<dim3(BB * LQ / 8), 256, 0, stream>>>(acc_buf, opw, opb, out);
  } else {
    int* idx_buf = (int*)d_ws;
    float* acc_buf = (float*)((char*)d_ws + IDXB);

    corr_topk_kernel<1><<<dim3(16, NL, BB * NH), 256, 0, stream>>>(
        query, value, idx_buf, (float4*)nullptr, (int4*)nullptr);
    loc_kernel<<<dim3((BB * LQ * NH * NL * K9) / 256), 256, 0, stream>>>(idx_buf, loc);
    gather_kernel<<<dim3(BB * LQ), 256, 0, stream>>>(value, idx_buf, acc_buf);
    proj_kernel<<<dim3(BB * LQ / 8), 256, 0, stream>>>(acc_buf, opw, opb, out);
  }
}

// Round 6
// 121.809 us; speedup vs baseline: 46.9538x; 46.9538x over previous
//
#include <hip/hip_runtime.h>
#include <math.h>

// Problem constants (MSDeformMatchV2HeaderAttn)
#define BB 2
#define LQ 1024
#define DM 256
#define NH 8
#define DH 32
#define NL 4
#define HWsp 1024   // 32*32
#define LIN 4096
#define K9 36

typedef short bf16x8 __attribute__((ext_vector_type(8)));
typedef float f32x4 __attribute__((ext_vector_type(4)));

// round-to-nearest-even fp32 -> bf16 bits
__device__ __forceinline__ ushort bf16rn(float x) {
  unsigned u = __float_as_uint(x);
  unsigned r = (u + 0x7FFFu + ((u >> 16) & 1u)) >> 16;
  return (ushort)r;
}
__device__ __forceinline__ float bf16tof(ushort h) {
  return __uint_as_float(((unsigned)h) << 16);
}

// stable top-4 insert (value desc, ascending scan order => lower index wins ties)
#define INSERT4(val, index)                                              \
  {                                                                      \
    const float v_ = (val);                                              \
    const int ix_ = (index);                                             \
    if (v_ > v3) {                                                       \
      if (v_ > v1) {                                                     \
        if (v_ > v0) {                                                   \
          v3 = v2; i3 = i2; v2 = v1; i2 = i1; v1 = v0; i1 = i0;          \
          v0 = v_; i0 = ix_;                                             \
        } else {                                                         \
          v3 = v2; i3 = i2; v2 = v1; i2 = i1; v1 = v_; i1 = ix_;         \
        }                                                                \
      } else {                                                           \
        if (v_ > v2) {                                                   \
          v3 = v2; i3 = i2; v2 = v_; i2 = ix_;                           \
        } else {                                                         \
          v3 = v_; i3 = ix_;                                             \
        }                                                                \
      }                                                                  \
    }                                                                    \
  }

// a := lexmax(a, b)  under (value desc, index asc)
#define LMAX(av, ai, bv, bi)                                        \
  {                                                                 \
    const bool g_ = ((av) > (bv)) || ((av) == (bv) && (ai) < (bi)); \
    if (!g_) { (av) = (bv); (ai) = (bi); }                          \
  }
// compare-exchange: order (a,b) so a >=lex b
#define CEX(av, ai, bv, bi)                                         \
  {                                                                 \
    const bool g_ = ((av) > (bv)) || ((av) == (bv) && (ai) < (bi)); \
    const float tv_ = g_ ? (av) : (bv);                             \
    const int ti_ = g_ ? (ai) : (bi);                               \
    (bv) = g_ ? (bv) : (av); (bi) = g_ ? (bi) : (ai);               \
    (av) = tv_; (ai) = ti_;                                         \
  }

// ---------------------------------------------------------------------------
// Kernel 1 (v5): corr + stable top-4 via bf16x3-split MFMA (16x16x32).
// corr_tile[k16][q16] = V_tile(16x32) . Q_tile(32x16) in ~fp32 accuracy:
//   x = x1+x2+x3 (bf16 parts); 6 MFMA terms accumulated smallest-first.
// Lane L: C col = q = L&15, rows k = t*16 + (L>>4)*4 + reg  (reg=0..3).
// Each lane keeps top-4 for ONE q-column (8 regs); merge over shfl_xor 16/32.
// Grid: (16 q-chunks of 64, 4 levels, 16 n*h) x 256 threads (4 waves).
// Wave w owns q-tile (blockIdx.x*4 + w); block stages V chunk (128 k) in LDS.
// ---------------------------------------------------------------------------
__global__ __launch_bounds__(256) void corr_topk_kernel(
    const float* __restrict__ query, const float* __restrict__ value,
    int* __restrict__ idx_out) {
  __shared__ ushort hiL[128][40];   // pad 40 -> 80B row stride (16B aligned)
  __shared__ ushort loL[128][40];
  __shared__ ushort lo2L[128][40];

  const int tid = threadIdx.x;
  const int nh = blockIdx.z;  // n*8+h
  const int n = nh >> 3, h = nh & 7;
  const int l = blockIdx.y;
  const int w = tid >> 6, L = tid & 63;
  const int qtile = (blockIdx.x << 2) + w;  // 0..63
  const int r16 = L & 15, g = L >> 4;       // C: col=r16(q), row-group g

  // ---- Q fragments (persistent): Q[qtile*16 + r16][h*32 + g*8 + j] ----
  bf16x8 qhi, qlo, qlo2;
  {
    const float* qp =
        query + (size_t)(n * LQ + (qtile << 4) + r16) * DM + h * DH + (g << 3);
    float qf[8];
    *(float4*)&qf[0] = *(const float4*)qp;
    *(float4*)&qf[4] = *(const float4*)(qp + 4);
    ushort uh[8], ul[8], ul2[8];
    #pragma unroll
    for (int j = 0; j < 8; ++j) {
      const float x = qf[j];
      const ushort h1 = bf16rn(x);
      const float r1 = x - bf16tof(h1);
      const ushort h2 = bf16rn(r1);
      const float r2 = r1 - bf16tof(h2);
      uh[j] = h1; ul[j] = h2; ul2[j] = bf16rn(r2);
    }
    qhi = (bf16x8){(short)uh[0], (short)uh[1], (short)uh[2], (short)uh[3],
                   (short)uh[4], (short)uh[5], (short)uh[6], (short)uh[7]};
    qlo = (bf16x8){(short)ul[0], (short)ul[1], (short)ul[2], (short)ul[3],
                   (short)ul[4], (short)ul[5], (short)ul[6], (short)ul[7]};
    qlo2 = (bf16x8){(short)ul2[0], (short)ul2[1], (short)ul2[2], (short)ul2[3],
                    (short)ul2[4], (short)ul2[5], (short)ul2[6], (short)ul2[7]};
  }

  float v0 = -INFINITY, v1 = -INFINITY, v2 = -INFINITY, v3 = -INFINITY;
  int i0 = 0, i1 = 0, i2 = 0, i3 = 0;

  const float* vbase = value + (size_t)(n * LIN + l * HWsp) * DM + h * DH;
  const int srow = tid >> 1, scol = (tid & 1) << 4;  // staging: 16 floats/thread

  for (int c = 0; c < 8; ++c) {
    // ---- stage V chunk (128 rows x 32 d) as bf16 hi/lo/lo2 ----
    {
      const float* vp = vbase + (size_t)((c << 7) + srow) * DM + scol;
      float xf[16];
      *(float4*)&xf[0] = *(const float4*)vp;
      *(float4*)&xf[4] = *(const float4*)(vp + 4);
      *(float4*)&xf[8] = *(const float4*)(vp + 8);
      *(float4*)&xf[12] = *(const float4*)(vp + 12);
      ushort uh[16], ul[16], ul2[16];
      #pragma unroll
      for (int j = 0; j < 16; ++j) {
        const float x = xf[j];
        const ushort h1 = bf16rn(x);
        const float r1 = x - bf16tof(h1);
        const ushort h2 = bf16rn(r1);
        const float r2 = r1 - bf16tof(h2);
        uh[j] = h1; ul[j] = h2; ul2[j] = bf16rn(r2);
      }
      #pragma unroll
      for (int hv = 0; hv < 2; ++hv) {
        const int o = hv << 3;
        *(bf16x8*)&hiL[srow][scol + o] =
            (bf16x8){(short)uh[o], (short)uh[o + 1], (short)uh[o + 2], (short)uh[o + 3],
                     (short)uh[o + 4], (short)uh[o + 5], (short)uh[o + 6], (short)uh[o + 7]};
        *(bf16x8*)&loL[srow][scol + o] =
            (bf16x8){(short)ul[o], (short)ul[o + 1], (short)ul[o + 2], (short)ul[o + 3],
                     (short)ul[o + 4], (short)ul[o + 5], (short)ul[o + 6], (short)ul[o + 7]};
        *(bf16x8*)&lo2L[srow][scol + o] =
            (bf16x8){(short)ul2[o], (short)ul2[o + 1], (short)ul2[o + 2], (short)ul2[o + 3],
                     (short)ul2[o + 4], (short)ul2[o + 5], (short)ul2[o + 6], (short)ul2[o + 7]};
      }
    }
    __syncthreads();

    // ---- compute: 8 k-tiles of 16; lane reads its A-frag (V) per part ----
    #pragma unroll
    for (int t = 0; t < 8; ++t) {
      const int row = (t << 4) + r16;
      const bf16x8 ahi = *(const bf16x8*)&hiL[row][g << 3];
      const bf16x8 alo = *(const bf16x8*)&loL[row][g << 3];
      const bf16x8 alo2 = *(const bf16x8*)&lo2L[row][g << 3];
      f32x4 acc = {0.f, 0.f, 0.f, 0.f};
      // smallest-first accumulation: lo2 terms, lo*lo, cross, main
      acc = __builtin_amdgcn_mfma_f32_16x16x32_bf16(alo2, qhi, acc, 0, 0, 0);
      acc = __builtin_amdgcn_mfma_f32_16x16x32_bf16(ahi, qlo2, acc, 0, 0, 0);
      acc = __builtin_amdgcn_mfma_f32_16x16x32_bf16(alo, qlo, acc, 0, 0, 0);
      acc = __builtin_amdgcn_mfma_f32_16x16x32_bf16(alo, qhi, acc, 0, 0, 0);
      acc = __builtin_amdgcn_mfma_f32_16x16x32_bf16(ahi, qlo, acc, 0, 0, 0);
      acc = __builtin_amdgcn_mfma_f32_16x16x32_bf16(ahi, qhi, acc, 0, 0, 0);
      const int kb = (c << 7) + (t << 4) + (g << 2);
      INSERT4(acc[0], kb + 0);
      INSERT4(acc[1], kb + 1);
      INSERT4(acc[2], kb + 2);
      INSERT4(acc[3], kb + 3);
    }
    __syncthreads();
  }

  // ---- merge the 4 row-groups of this q-column (lanes L, L^16, L^32) ----
  #pragma unroll
  for (int m = 16; m < 64; m <<= 1) {
    const float b0 = __shfl_xor(v0, m);
    const float b1 = __shfl_xor(v1, m);
    const float b2 = __shfl_xor(v2, m);
    const float b3 = __shfl_xor(v3, m);
    const int j0 = __shfl_xor(i0, m);
    const int j1 = __shfl_xor(i1, m);
    const int j2 = __shfl_xor(i2, m);
    const int j3 = __shfl_xor(i3, m);
    LMAX(v0, i0, b3, j3);
    LMAX(v1, i1, b2, j2);
    LMAX(v2, i2, b1, j1);
    LMAX(v3, i3, b0, j0);
    CEX(v0, i0, v2, i2);
    CEX(v1, i1, v3, i3);
    CEX(v0, i0, v1, i1);
    CEX(v2, i2, v3, i3);
  }

  if (L < 16) {
    const int q = (qtile << 4) + L;
    // idx_buf layout: [n][h][l][q][4] int32
    ((int4*)idx_out)[(((size_t)nh * NL + l) << 10) + q] = make_int4(i0, i1, i2, i3);
  }
}

// ---------------------------------------------------------------------------
// Kernel 2: loc output. res=clip(idx+delta,0,961); loc=(res>>5, res&31)/32.
// ---------------------------------------------------------------------------
__global__ __launch_bounds__(256) void loc_kernel(const int* __restrict__ idx_buf,
                                                  float* __restrict__ loc) {
  const int t = blockIdx.x * 256 + threadIdx.x;  // < 2359296
  const int k = t % 36;
  int rest = t / 36;
  const int l = rest & 3; rest >>= 2;
  const int h = rest & 7; rest >>= 3;
  const int q = rest & 1023;
  const int n = rest >> 10;
  const int p = k & 3, dd = k >> 2;  // delta-major: k = dd*4 + p
  const int idx = idx_buf[(((((n << 3) + h) * NL + l) << 10) + q) * 4 + p];
  const int delta = ((dd / 3) - 1) * 32 + (dd % 3) - 1;  // {-33,-32,-31,-1,0,1,31,32,33}
  int res = idx + delta;
  res = min(max(res, 0), 961);
  const int W = res >> 5, H = res & 31;
  ((float2*)loc)[t] = make_float2((float)W * 0.03125f, (float)H * 0.03125f);
}

// ---------------------------------------------------------------------------
// Kernel 3: gather+average (unchanged from R1-validated version).
// ---------------------------------------------------------------------------
__global__ __launch_bounds__(256) void gather_kernel(
    const float* __restrict__ value, const int* __restrict__ idx_buf,
    float* __restrict__ acc_out) {
  __shared__ float red[NL][DM];
  const int nq = blockIdx.x;  // n*1024+q
  const int n = nq >> 10, q = nq & 1023;
  const int tid = threadIdx.x;
  const int l = tid >> 6;
  const int h = (tid >> 3) & 7;
  const int d4 = tid & 7;

  const int4 id4 =
      ((const int4*)idx_buf)[((((size_t)((n << 3) + h)) * NL + l) << 10) + q];

  const float4* vb4 =
      (const float4*)(value + (size_t)(n * LIN + l * HWsp) * DM + h * DH) + d4;

  float4 a = make_float4(0.f, 0.f, 0.f, 0.f);
  #pragma unroll
  for (int p = 0; p < 4; ++p) {
    const int idx = (p == 0) ? id4.x : (p == 1) ? id4.y : (p == 2) ? id4.z : id4.w;
    #pragma unroll
    for (int dy = -1; dy <= 1; ++dy) {
      #pragma unroll
      for (int dx = -1; dx <= 1; ++dx) {
        int res = idx + dy * 32 + dx;
        res = min(max(res, 0), 961);
        const int W = res >> 5, H = res & 31;
        const int g = (H << 5) + W;
        const float wW = (W >= 1) ? 1.f : 0.f;
        const float wH = (H >= 1) ? 1.f : 0.f;
        const float wB = wW * wH;
        const float4 c0 = vb4[(size_t)g * 64];
        const float4 c1 = vb4[(size_t)max(g - 1, 0) * 64];
        const float4 c2 = vb4[(size_t)max(g - 32, 0) * 64];
        const float4 c3 = vb4[(size_t)max(g - 33, 0) * 64];
        a.x += c0.x + wW * c1.x + wH * c2.x + wB * c3.x;
        a.y += c0.y + wW * c1.y + wH * c2.y + wB * c3.y;
        a.z += c0.z + wW * c1.z + wH * c2.z + wB * c3.z;
        a.w += c0.w + wW * c1.w + wH * c2.w + wB * c3.w;
      }
    }
  }

  const int col = h * DH + d4 * 4;
  red[l][col + 0] = a.x;
  red[l][col + 1] = a.y;
  red[l][col + 2] = a.z;
  red[l][col + 3] = a.w;
  __syncthreads();
  const float s = red[0][tid] + red[1][tid] + red[2][tid] + red[3][tid];
  acc_out[(size_t)nq * DM + tid] = s * (1.0f / 576.0f);
}

// ---------------------------------------------------------------------------
// Kernel 4: out = acc @ W^T + b.  256 blocks x 256 threads, 8 q-rows/block.
// ---------------------------------------------------------------------------
__global__ __launch_bounds__(256) void proj_kernel(
    const float* __restrict__ acc_in, const float* __restrict__ W,
    const float* __restrict__ bias, float* __restrict__ out) {
  __shared__ float la[8][256];
  const int qb = blockIdx.x << 3;
  const int tid = threadIdx.x;
  for (int i = tid; i < 8 * 256; i += 256)
    la[i >> 8][i & 255] = acc_in[((size_t)qb << 8) + i];
  __syncthreads();
  const float* wrow = W + (size_t)tid * 256;
  float s0 = 0.f, s1 = 0.f, s2 = 0.f, s3 = 0.f, s4 = 0.f, s5 = 0.f, s6 = 0.f, s7 = 0.f;
  for (int c0 = 0; c0 < 256; c0 += 4) {
    const float4 wv = *(const float4*)(wrow + c0);
    #define PROJ_STEP(qi, sreg)                                   \
      {                                                           \
        const float4 av = *(const float4*)&la[qi][c0];            \
        sreg = fmaf(wv.x, av.x, sreg);                            \
        sreg = fmaf(wv.y, av.y, sreg);                            \
        sreg = fmaf(wv.z, av.z, sreg);                            \
        sreg = fmaf(wv.w, av.w, sreg);                            \
      }
    PROJ_STEP(0, s0) PROJ_STEP(1, s1) PROJ_STEP(2, s2) PROJ_STEP(3, s3)
    PROJ_STEP(4, s4) PROJ_STEP(5, s5) PROJ_STEP(6, s6) PROJ_STEP(7, s7)
    #undef PROJ_STEP
  }
  const float bj = bias[tid];
  out[(size_t)(qb + 0) * 256 + tid] = s0 + bj;
  out[(size_t)(qb + 1) * 256 + tid] = s1 + bj;
  out[(size_t)(qb + 2) * 256 + tid] = s2 + bj;
  out[(size_t)(qb + 3) * 256 + tid] = s3 + bj;
  out[(size_t)(qb + 4) * 256 + tid] = s4 + bj;
  out[(size_t)(qb + 5) * 256 + tid] = s5 + bj;
  out[(size_t)(qb + 6) * 256 + tid] = s6 + bj;
  out[(size_t)(qb + 7) * 256 + tid] = s7 + bj;
}

// ---------------------------------------------------------------------------
extern "C" void kernel_launch(void* const* d_in, const int* in_sizes, int n_in,
                              void* d_out, int out_size, void* d_ws, size_t ws_size,
                              hipStream_t stream) {
  (void)in_sizes; (void)n_in; (void)out_size; (void)ws_size;
  const float* query = (const float*)d_in[0];
  const float* value = (const float*)d_in[2];
  const float* opw = (const float*)d_in[5];
  const float* opb = (const float*)d_in[6];

  float* out = (float*)d_out;               // [2,1024,256]
  float* loc = out + (size_t)BB * LQ * DM;  // [2,1024,8,4,36,2]

  int* idx_buf = (int*)d_ws;  // 1 MB
  float* acc_buf =
      (float*)((char*)d_ws + (size_t)BB * NH * NL * LQ * 4 * sizeof(int));

  corr_topk_kernel<<<dim3(16, NL, BB * NH), 256, 0, stream>>>(query, value, idx_buf);
  loc_kernel<<<dim3((BB * LQ * NH * NL * K9) / 256), 256, 0, stream>>>(idx_buf, loc);
  gather_kernel<<<dim3(BB * LQ), 256, 0, stream>>>(value, idx_buf, acc_buf);
  proj_kernel<<<dim3(BB * LQ / 8), 256, 0, stream>>>(acc_buf, opw, opb, out);
}

// Round 7
// 120.286 us; speedup vs baseline: 47.5483x; 1.0127x over previous
//
#include <hip/hip_runtime.h>
#include <math.h>

// Problem constants (MSDeformMatchV2HeaderAttn)
#define BB 2
#define LQ 1024
#define DM 256
#define NH 8
#define DH 32
#define NL 4
#define HWsp 1024   // 32*32
#define LIN 4096
#define K9 36

typedef short bf16x8 __attribute__((ext_vector_type(8)));
typedef float f32x4 __attribute__((ext_vector_type(4)));

// round-to-nearest-even fp32 -> bf16 bits
__device__ __forceinline__ ushort bf16rn(float x) {
  unsigned u = __float_as_uint(x);
  unsigned r = (u + 0x7FFFu + ((u >> 16) & 1u)) >> 16;
  return (ushort)r;
}
__device__ __forceinline__ float bf16tof(ushort h) {
  return __uint_as_float(((unsigned)h) << 16);
}

// stable top-4 insert (value desc, ascending scan order => lower index wins ties)
#define INSERT4(val, index)                                              \
  {                                                                      \
    const float v_ = (val);                                              \
    const int ix_ = (index);                                             \
    if (v_ > v3) {                                                       \
      if (v_ > v1) {                                                     \
        if (v_ > v0) {                                                   \
          v3 = v2; i3 = i2; v2 = v1; i2 = i1; v1 = v0; i1 = i0;          \
          v0 = v_; i0 = ix_;                                             \
        } else {                                                         \
          v3 = v2; i3 = i2; v2 = v1; i2 = i1; v1 = v_; i1 = ix_;         \
        }                                                                \
      } else {                                                           \
        if (v_ > v2) {                                                   \
          v3 = v2; i3 = i2; v2 = v_; i2 = ix_;                           \
        } else {                                                         \
          v3 = v_; i3 = ix_;                                             \
        }                                                                \
      }                                                                  \
    }                                                                    \
  }

// a := lexmax(a, b)  under (value desc, index asc)
#define LMAX(av, ai, bv, bi)                                        \
  {                                                                 \
    const bool g_ = ((av) > (bv)) || ((av) == (bv) && (ai) < (bi)); \
    if (!g_) { (av) = (bv); (ai) = (bi); }                          \
  }
// compare-exchange: order (a,b) so a >=lex b
#define CEX(av, ai, bv, bi)                                         \
  {                                                                 \
    const bool g_ = ((av) > (bv)) || ((av) == (bv) && (ai) < (bi)); \
    const float tv_ = g_ ? (av) : (bv);                             \
    const int ti_ = g_ ? (ai) : (bi);                               \
    (bv) = g_ ? (bv) : (av); (bi) = g_ ? (bi) : (ai);               \
    (av) = tv_; (ai) = ti_;                                         \
  }

// per-plane ushort stride of the presplit buffer
#define PSTRIDE ((size_t)BB * NL * NH * 1024 * 32)  // 2,097,152

// ---------------------------------------------------------------------------
// Kernel 0: one-shot bf16x3 split of value into 3 planes, head-major layout:
// vs[part][n][l][h][row(1024)][32] ushort  -> chunk staging is contiguous.
// Grid: 1024 x 256, 8 elements/thread.
// ---------------------------------------------------------------------------
__global__ __launch_bounds__(256) void vsplit_kernel(
    const float* __restrict__ value, ushort* __restrict__ vs) {
  const int T = blockIdx.x * 256 + threadIdx.x;  // < 262144
  const int flat = T << 3;                       // element index, 8-aligned
  const int n = flat >> 20;                      // LIN*DM = 2^20
  const int rem = flat & 0xFFFFF;
  const int lin = rem >> 8;
  const int d0 = rem & 255;
  const int l = lin >> 10, row = lin & 1023;
  const int h = d0 >> 5, dd = d0 & 31;

  const float* src = value + (size_t)flat;
  float xf[8];
  *(float4*)&xf[0] = *(const float4*)src;
  *(float4*)&xf[4] = *(const float4*)(src + 4);

  ushort uh[8], ul[8], ul2[8];
  #pragma unroll
  for (int j = 0; j < 8; ++j) {
    const float x = xf[j];
    const ushort h1 = bf16rn(x);
    const float r1 = x - bf16tof(h1);
    const ushort h2 = bf16rn(r1);
    const float r2 = r1 - bf16tof(h2);
    uh[j] = h1; ul[j] = h2; ul2[j] = bf16rn(r2);
  }
  const size_t ob =
      ((((size_t)((n * NL + l) * NH + h)) << 10) + row) * 32 + dd;
  *(bf16x8*)(vs + 0 * PSTRIDE + ob) =
      (bf16x8){(short)uh[0], (short)uh[1], (short)uh[2], (short)uh[3],
               (short)uh[4], (short)uh[5], (short)uh[6], (short)uh[7]};
  *(bf16x8*)(vs + 1 * PSTRIDE + ob) =
      (bf16x8){(short)ul[0], (short)ul[1], (short)ul[2], (short)ul[3],
               (short)ul[4], (short)ul[5], (short)ul[6], (short)ul[7]};
  *(bf16x8*)(vs + 2 * PSTRIDE + ob) =
      (bf16x8){(short)ul2[0], (short)ul2[1], (short)ul2[2], (short)ul2[3],
               (short)ul2[4], (short)ul2[5], (short)ul2[6], (short)ul2[7]};
}

// ---------------------------------------------------------------------------
// Kernel 1 (v6): corr + stable top-4 via bf16x3-split MFMA (16x16x32).
// PRESPLIT=1: stage pre-split bf16 planes (pure copy). PRESPLIT=0: R5 path
// (convert fp32->bf16x3 in-kernel) as ws fallback.
// Lane L: C col = q = L&15, rows k = t*16 + (L>>4)*4 + reg  (reg=0..3).
// Each lane keeps top-4 for ONE q-column; merge over shfl_xor 16/32.
// Grid: (16 q-chunks of 64, 4 levels, 16 n*h) x 256 threads (4 waves).
// ---------------------------------------------------------------------------
template <int PRESPLIT>
__global__ __launch_bounds__(256) void corr_topk_kernel(
    const float* __restrict__ query, const float* __restrict__ value,
    const ushort* __restrict__ vs, int* __restrict__ idx_out) {
  __shared__ ushort hiL[128][40];  // pad 40 -> 80B row stride (16B aligned)
  __shared__ ushort loL[128][40];
  __shared__ ushort lo2L[128][40];

  const int tid = threadIdx.x;
  const int nh = blockIdx.z;  // n*8+h
  const int n = nh >> 3, h = nh & 7;
  const int l = blockIdx.y;
  const int w = tid >> 6, L = tid & 63;
  const int qtile = (blockIdx.x << 2) + w;  // 0..63
  const int r16 = L & 15, g = L >> 4;       // C: col=r16(q), row-group g

  // ---- Q fragments (persistent): Q[qtile*16 + r16][h*32 + g*8 + j] ----
  bf16x8 qhi, qlo, qlo2;
  {
    const float* qp =
        query + (size_t)(n * LQ + (qtile << 4) + r16) * DM + h * DH + (g << 3);
    float qf[8];
    *(float4*)&qf[0] = *(const float4*)qp;
    *(float4*)&qf[4] = *(const float4*)(qp + 4);
    ushort uh[8], ul[8], ul2[8];
    #pragma unroll
    for (int j = 0; j < 8; ++j) {
      const float x = qf[j];
      const ushort h1 = bf16rn(x);
      const float r1 = x - bf16tof(h1);
      const ushort h2 = bf16rn(r1);
      const float r2 = r1 - bf16tof(h2);
      uh[j] = h1; ul[j] = h2; ul2[j] = bf16rn(r2);
    }
    qhi = (bf16x8){(short)uh[0], (short)uh[1], (short)uh[2], (short)uh[3],
                   (short)uh[4], (short)uh[5], (short)uh[6], (short)uh[7]};
    qlo = (bf16x8){(short)ul[0], (short)ul[1], (short)ul[2], (short)ul[3],
                   (short)ul[4], (short)ul[5], (short)ul[6], (short)ul[7]};
    qlo2 = (bf16x8){(short)ul2[0], (short)ul2[1], (short)ul2[2], (short)ul2[3],
                    (short)ul2[4], (short)ul2[5], (short)ul2[6], (short)ul2[7]};
  }

  float v0 = -INFINITY, v1 = -INFINITY, v2 = -INFINITY, v3 = -INFINITY;
  int i0 = 0, i1 = 0, i2 = 0, i3 = 0;

  // staging sources
  const float* vbase = value + (size_t)(n * LIN + l * HWsp) * DM + h * DH;
  const ushort* psbase =
      vs + ((((size_t)((n * NL + l) * NH + h)) << 10)) * 32;  // row 0, d 0
  const int srow = tid >> 1, scol = (tid & 1) << 4;

  for (int c = 0; c < 8; ++c) {
    if (PRESPLIT) {
      // ---- pure-copy staging: 32 B per thread per plane, coalesced ----
      const size_t off = ((size_t)(c << 7)) * 32 + ((size_t)tid << 4);
      const ushort* s_hi = psbase + off;
      const ushort* s_lo = psbase + PSTRIDE + off;
      const ushort* s_lo2 = psbase + 2 * PSTRIDE + off;
      *(bf16x8*)&hiL[srow][scol] = *(const bf16x8*)s_hi;
      *(bf16x8*)&hiL[srow][scol + 8] = *(const bf16x8*)(s_hi + 8);
      *(bf16x8*)&loL[srow][scol] = *(const bf16x8*)s_lo;
      *(bf16x8*)&loL[srow][scol + 8] = *(const bf16x8*)(s_lo + 8);
      *(bf16x8*)&lo2L[srow][scol] = *(const bf16x8*)s_lo2;
      *(bf16x8*)&lo2L[srow][scol + 8] = *(const bf16x8*)(s_lo2 + 8);
    } else {
      // ---- fallback: convert fp32 -> bf16x3 in-kernel (R5 path) ----
      const float* vp = vbase + (size_t)((c << 7) + srow) * DM + scol;
      float xf[16];
      *(float4*)&xf[0] = *(const float4*)vp;
      *(float4*)&xf[4] = *(const float4*)(vp + 4);
      *(float4*)&xf[8] = *(const float4*)(vp + 8);
      *(float4*)&xf[12] = *(const float4*)(vp + 12);
      ushort uh[16], ul[16], ul2[16];
      #pragma unroll
      for (int j = 0; j < 16; ++j) {
        const float x = xf[j];
        const ushort h1 = bf16rn(x);
        const float r1 = x - bf16tof(h1);
        const ushort h2 = bf16rn(r1);
        const float r2 = r1 - bf16tof(h2);
        uh[j] = h1; ul[j] = h2; ul2[j] = bf16rn(r2);
      }
      #pragma unroll
      for (int hv = 0; hv < 2; ++hv) {
        const int o = hv << 3;
        *(bf16x8*)&hiL[srow][scol + o] =
            (bf16x8){(short)uh[o], (short)uh[o + 1], (short)uh[o + 2], (short)uh[o + 3],
                     (short)uh[o + 4], (short)uh[o + 5], (short)uh[o + 6], (short)uh[o + 7]};
        *(bf16x8*)&loL[srow][scol + o] =
            (bf16x8){(short)ul[o], (short)ul[o + 1], (short)ul[o + 2], (short)ul[o + 3],
                     (short)ul[o + 4], (short)ul[o + 5], (short)ul[o + 6], (short)ul[o + 7]};
        *(bf16x8*)&lo2L[srow][scol + o] =
            (bf16x8){(short)ul2[o], (short)ul2[o + 1], (short)ul2[o + 2], (short)ul2[o + 3],
                     (short)ul2[o + 4], (short)ul2[o + 5], (short)ul2[o + 6], (short)ul2[o + 7]};
      }
    }
    __syncthreads();

    // ---- compute: 8 k-tiles of 16; lane reads its A-frag (V) per part ----
    #pragma unroll
    for (int t = 0; t < 8; ++t) {
      const int row = (t << 4) + r16;
      const bf16x8 ahi = *(const bf16x8*)&hiL[row][g << 3];
      const bf16x8 alo = *(const bf16x8*)&loL[row][g << 3];
      const bf16x8 alo2 = *(const bf16x8*)&lo2L[row][g << 3];
      f32x4 acc = {0.f, 0.f, 0.f, 0.f};
      // smallest-first accumulation: lo2 terms, lo*lo, cross, main
      acc = __builtin_amdgcn_mfma_f32_16x16x32_bf16(alo2, qhi, acc, 0, 0, 0);
      acc = __builtin_amdgcn_mfma_f32_16x16x32_bf16(ahi, qlo2, acc, 0, 0, 0);
      acc = __builtin_amdgcn_mfma_f32_16x16x32_bf16(alo, qlo, acc, 0, 0, 0);
      acc = __builtin_amdgcn_mfma_f32_16x16x32_bf16(alo, qhi, acc, 0, 0, 0);
      acc = __builtin_amdgcn_mfma_f32_16x16x32_bf16(ahi, qlo, acc, 0, 0, 0);
      acc = __builtin_amdgcn_mfma_f32_16x16x32_bf16(ahi, qhi, acc, 0, 0, 0);
      const int kb = (c << 7) + (t << 4) + (g << 2);
      INSERT4(acc[0], kb + 0);
      INSERT4(acc[1], kb + 1);
      INSERT4(acc[2], kb + 2);
      INSERT4(acc[3], kb + 3);
    }
    __syncthreads();
  }

  // ---- merge the 4 row-groups of this q-column (lanes L, L^16, L^32) ----
  #pragma unroll
  for (int m = 16; m < 64; m <<= 1) {
    const float b0 = __shfl_xor(v0, m);
    const float b1 = __shfl_xor(v1, m);
    const float b2 = __shfl_xor(v2, m);
    const float b3 = __shfl_xor(v3, m);
    const int j0 = __shfl_xor(i0, m);
    const int j1 = __shfl_xor(i1, m);
    const int j2 = __shfl_xor(i2, m);
    const int j3 = __shfl_xor(i3, m);
    LMAX(v0, i0, b3, j3);
    LMAX(v1, i1, b2, j2);
    LMAX(v2, i2, b1, j1);
    LMAX(v3, i3, b0, j0);
    CEX(v0, i0, v2, i2);
    CEX(v1, i1, v3, i3);
    CEX(v0, i0, v1, i1);
    CEX(v2, i2, v3, i3);
  }

  if (L < 16) {
    const int q = (qtile << 4) + L;
    // idx_buf layout: [n][h][l][q][4] int32
    ((int4*)idx_out)[(((size_t)nh * NL + l) << 10) + q] = make_int4(i0, i1, i2, i3);
  }
}

// ---------------------------------------------------------------------------
// Kernel 2: loc output. res=clip(idx+delta,0,961); loc=(res>>5, res&31)/32.
// ---------------------------------------------------------------------------
__global__ __launch_bounds__(256) void loc_kernel(const int* __restrict__ idx_buf,
                                                  float* __restrict__ loc) {
  const int t = blockIdx.x * 256 + threadIdx.x;  // < 2359296
  const int k = t % 36;
  int rest = t / 36;
  const int l = rest & 3; rest >>= 2;
  const int h = rest & 7; rest >>= 3;
  const int q = rest & 1023;
  const int n = rest >> 10;
  const int p = k & 3, dd = k >> 2;  // delta-major: k = dd*4 + p
  const int idx = idx_buf[(((((n << 3) + h) * NL + l) << 10) + q) * 4 + p];
  const int delta = ((dd / 3) - 1) * 32 + (dd % 3) - 1;  // {-33,-32,-31,-1,0,1,31,32,33}
  int res = idx + delta;
  res = min(max(res, 0), 961);
  const int W = res >> 5, H = res & 31;
  ((float2*)loc)[t] = make_float2((float)W * 0.03125f, (float)H * 0.03125f);
}

// ---------------------------------------------------------------------------
// Kernel 3: gather+average (R1-validated).
// ---------------------------------------------------------------------------
__global__ __launch_bounds__(256) void gather_kernel(
    const float* __restrict__ value, const int* __restrict__ idx_buf,
    float* __restrict__ acc_out) {
  __shared__ float red[NL][DM];
  const int nq = blockIdx.x;  // n*1024+q
  const int n = nq >> 10, q = nq & 1023;
  const int tid = threadIdx.x;
  const int l = tid >> 6;
  const int h = (tid >> 3) & 7;
  const int d4 = tid & 7;

  const int4 id4 =
      ((const int4*)idx_buf)[((((size_t)((n << 3) + h)) * NL + l) << 10) + q];

  const float4* vb4 =
      (const float4*)(value + (size_t)(n * LIN + l * HWsp) * DM + h * DH) + d4;

  float4 a = make_float4(0.f, 0.f, 0.f, 0.f);
  #pragma unroll
  for (int p = 0; p < 4; ++p) {
    const int idx = (p == 0) ? id4.x : (p == 1) ? id4.y : (p == 2) ? id4.z : id4.w;
    #pragma unroll
    for (int dy = -1; dy <= 1; ++dy) {
      #pragma unroll
      for (int dx = -1; dx <= 1; ++dx) {
        int res = idx + dy * 32 + dx;
        res = min(max(res, 0), 961);
        const int W = res >> 5, H = res & 31;
        const int g = (H << 5) + W;
        const float wW = (W >= 1) ? 1.f : 0.f;
        const float wH = (H >= 1) ? 1.f : 0.f;
        const float wB = wW * wH;
        const float4 c0 = vb4[(size_t)g * 64];
        const float4 c1 = vb4[(size_t)max(g - 1, 0) * 64];
        const float4 c2 = vb4[(size_t)max(g - 32, 0) * 64];
        const float4 c3 = vb4[(size_t)max(g - 33, 0) * 64];
        a.x += c0.x + wW * c1.x + wH * c2.x + wB * c3.x;
        a.y += c0.y + wW * c1.y + wH * c2.y + wB * c3.y;
        a.z += c0.z + wW * c1.z + wH * c2.z + wB * c3.z;
        a.w += c0.w + wW * c1.w + wH * c2.w + wB * c3.w;
      }
    }
  }

  const int col = h * DH + d4 * 4;
  red[l][col + 0] = a.x;
  red[l][col + 1] = a.y;
  red[l][col + 2] = a.z;
  red[l][col + 3] = a.w;
  __syncthreads();
  const float s = red[0][tid] + red[1][tid] + red[2][tid] + red[3][tid];
  acc_out[(size_t)nq * DM + tid] = s * (1.0f / 576.0f);
}

// ---------------------------------------------------------------------------
// Kernel 4: out = acc @ W^T + b.  256 blocks x 256 threads, 8 q-rows/block.
// ---------------------------------------------------------------------------
__global__ __launch_bounds__(256) void proj_kernel(
    const float* __restrict__ acc_in, const float* __restrict__ W,
    const float* __restrict__ bias, float* __restrict__ out) {
  __shared__ float la[8][256];
  const int qb = blockIdx.x << 3;
  const int tid = threadIdx.x;
  for (int i = tid; i < 8 * 256; i += 256)
    la[i >> 8][i & 255] = acc_in[((size_t)qb << 8) + i];
  __syncthreads();
  const float* wrow = W + (size_t)tid * 256;
  float s0 = 0.f, s1 = 0.f, s2 = 0.f, s3 = 0.f, s4 = 0.f, s5 = 0.f, s6 = 0.f, s7 = 0.f;
  for (int c0 = 0; c0 < 256; c0 += 4) {
    const float4 wv = *(const float4*)(wrow + c0);
    #define PROJ_STEP(qi, sreg)                                   \
      {                                                           \
        const float4 av = *(const float4*)&la[qi][c0];            \
        sreg = fmaf(wv.x, av.x, sreg);                            \
        sreg = fmaf(wv.y, av.y, sreg);                            \
        sreg = fmaf(wv.z, av.z, sreg);                            \
        sreg = fmaf(wv.w, av.w, sreg);                            \
      }
    PROJ_STEP(0, s0) PROJ_STEP(1, s1) PROJ_STEP(2, s2) PROJ_STEP(3, s3)
    PROJ_STEP(4, s4) PROJ_STEP(5, s5) PROJ_STEP(6, s6) PROJ_STEP(7, s7)
    #undef PROJ_STEP
  }
  const float bj = bias[tid];
  out[(size_t)(qb + 0) * 256 + tid] = s0 + bj;
  out[(size_t)(qb + 1) * 256 + tid] = s1 + bj;
  out[(size_t)(qb + 2) * 256 + tid] = s2 + bj;
  out[(size_t)(qb + 3) * 256 + tid] = s3 + bj;
  out[(size_t)(qb + 4) * 256 + tid] = s4 + bj;
  out[(size_t)(qb + 5) * 256 + tid] = s5 + bj;
  out[(size_t)(qb + 6) * 256 + tid] = s6 + bj;
  out[(size_t)(qb + 7) * 256 + tid] = s7 + bj;
}

// ---------------------------------------------------------------------------
extern "C" void kernel_launch(void* const* d_in, const int* in_sizes, int n_in,
                              void* d_out, int out_size, void* d_ws, size_t ws_size,
                              hipStream_t stream) {
  (void)in_sizes; (void)n_in; (void)out_size;
  const float* query = (const float*)d_in[0];
  const float* value = (const float*)d_in[2];
  const float* opw = (const float*)d_in[5];
  const float* opb = (const float*)d_in[6];

  float* out = (float*)d_out;               // [2,1024,256]
  float* loc = out + (size_t)BB * LQ * DM;  // [2,1024,8,4,36,2]

  const size_t SPLITB = 3 * PSTRIDE * sizeof(ushort);               // 12.58 MB
  const size_t IDXB = (size_t)BB * NH * NL * LQ * 4 * sizeof(int);  // 1 MB
  const size_t ACCB = (size_t)BB * LQ * DM * sizeof(float);         // 2 MB

  if (ws_size >= SPLITB + IDXB + ACCB) {
    ushort* vs = (ushort*)d_ws;
    int* idx_buf = (int*)((char*)d_ws + SPLITB);
    float* acc_buf = (float*)((char*)d_ws + SPLITB + IDXB);

    vsplit_kernel<<<dim3(1024), 256, 0, stream>>>(value, vs);
    corr_topk_kernel<1><<<dim3(16, NL, BB * NH), 256, 0, stream>>>(
        query, value, vs, idx_buf);
    loc_kernel<<<dim3((BB * LQ * NH * NL * K9) / 256), 256, 0, stream>>>(idx_buf, loc);
    gather_kernel<<<dim3(BB * LQ), 256, 0, stream>>>(value, idx_buf, acc_buf);
    proj_kernel<<<dim3(BB * LQ / 8), 256, 0, stream>>>(acc_buf, opw, opb, out);
  } else {
    int* idx_buf = (int*)d_ws;
    float* acc_buf = (float*)((char*)d_ws + IDXB);

    corr_topk_kernel<0><<<dim3(16, NL, BB * NH), 256, 0, stream>>>(
        query, value, (const ushort*)nullptr, idx_buf);
    loc_kernel<<<dim3((BB * LQ * NH * NL * K9) / 256), 256, 0, stream>>>(idx_buf, loc);
    gather_kernel<<<dim3(BB * LQ), 256, 0, stream>>>(value, idx_buf, acc_buf);
    proj_kernel<<<dim3(BB * LQ / 8), 256, 0, stream>>>(acc_buf, opw, opb, out);
  }
}

// Round 8
// 104.418 us; speedup vs baseline: 54.7738x; 1.1520x over previous
//
#include <hip/hip_runtime.h>
#include <math.h>

// Problem constants (MSDeformMatchV2HeaderAttn)
#define BB 2
#define LQ 1024
#define DM 256
#define NH 8
#define DH 32
#define NL 4
#define HWsp 1024   // 32*32
#define LIN 4096
#define K9 36
#define NGRP (BB * NH * NL * LQ)  // 65536 groups

typedef short bf16x8 __attribute__((ext_vector_type(8)));
typedef float f32x4 __attribute__((ext_vector_type(4)));

// round-to-nearest-even fp32 -> bf16 bits
__device__ __forceinline__ ushort bf16rn(float x) {
  unsigned u = __float_as_uint(x);
  unsigned r = (u + 0x7FFFu + ((u >> 16) & 1u)) >> 16;
  return (ushort)r;
}
__device__ __forceinline__ float bf16tof(ushort h) {
  return __uint_as_float(((unsigned)h) << 16);
}

// stable top-4 insert (value desc; ascending scan order => lower index wins ties)
#define INSERT4(val, index)                                              \
  {                                                                      \
    const float v_ = (val);                                              \
    const int ix_ = (index);                                             \
    if (v_ > v3) {                                                       \
      if (v_ > v1) {                                                     \
        if (v_ > v0) {                                                   \
          v3 = v2; i3 = i2; v2 = v1; i2 = i1; v1 = v0; i1 = i0;          \
          v0 = v_; i0 = ix_;                                             \
        } else {                                                         \
          v3 = v2; i3 = i2; v2 = v1; i2 = i1; v1 = v_; i1 = ix_;         \
        }                                                                \
      } else {                                                           \
        if (v_ > v2) {                                                   \
          v3 = v2; i3 = i2; v2 = v_; i2 = ix_;                           \
        } else {                                                         \
          v3 = v_; i3 = ix_;                                             \
        }                                                                \
      }                                                                  \
    }                                                                    \
  }

// a := lexmax(a, b)  under (value desc, index asc)
#define LMAX(av, ai, bv, bi)                                        \
  {                                                                 \
    const bool g_ = ((av) > (bv)) || ((av) == (bv) && (ai) < (bi)); \
    if (!g_) { (av) = (bv); (ai) = (bi); }                          \
  }
// compare-exchange: order (a,b) so a >=lex b
#define CEX(av, ai, bv, bi)                                         \
  {                                                                 \
    const bool g_ = ((av) > (bv)) || ((av) == (bv) && (ai) < (bi)); \
    const float tv_ = g_ ? (av) : (bv);                             \
    const int ti_ = g_ ? (ai) : (bi);                               \
    (bv) = g_ ? (bv) : (av); (bi) = g_ ? (bi) : (ai);               \
    (av) = tv_; (ai) = ti_;                                         \
  }

// per-plane ushort stride of the presplit buffer
#define PSTRIDE ((size_t)BB * NL * NH * 1024 * 32)  // 2,097,152

// ---------------------------------------------------------------------------
// Kernel 0: one-shot bf16x3 split of value, head-major layout:
// vs[part][n][l][h][row(1024)][32] ushort.
// ---------------------------------------------------------------------------
__global__ __launch_bounds__(256) void vsplit_kernel(
    const float* __restrict__ value, ushort* __restrict__ vs) {
  const int T = blockIdx.x * 256 + threadIdx.x;  // < 262144
  const int flat = T << 3;
  const int n = flat >> 20;
  const int rem = flat & 0xFFFFF;
  const int lin = rem >> 8;
  const int d0 = rem & 255;
  const int l = lin >> 10, row = lin & 1023;
  const int h = d0 >> 5, dd = d0 & 31;

  const float* src = value + (size_t)flat;
  float xf[8];
  *(float4*)&xf[0] = *(const float4*)src;
  *(float4*)&xf[4] = *(const float4*)(src + 4);

  ushort uh[8], ul[8], ul2[8];
  #pragma unroll
  for (int j = 0; j < 8; ++j) {
    const float x = xf[j];
    const ushort h1 = bf16rn(x);
    const float r1 = x - bf16tof(h1);
    const ushort h2 = bf16rn(r1);
    const float r2 = r1 - bf16tof(h2);
    uh[j] = h1; ul[j] = h2; ul2[j] = bf16rn(r2);
  }
  const size_t ob = ((((size_t)((n * NL + l) * NH + h)) << 10) + row) * 32 + dd;
  *(bf16x8*)(vs + 0 * PSTRIDE + ob) =
      (bf16x8){(short)uh[0], (short)uh[1], (short)uh[2], (short)uh[3],
               (short)uh[4], (short)uh[5], (short)uh[6], (short)uh[7]};
  *(bf16x8*)(vs + 1 * PSTRIDE + ob) =
      (bf16x8){(short)ul[0], (short)ul[1], (short)ul[2], (short)ul[3],
               (short)ul[4], (short)ul[5], (short)ul[6], (short)ul[7]};
  *(bf16x8*)(vs + 2 * PSTRIDE + ob) =
      (bf16x8){(short)ul2[0], (short)ul2[1], (short)ul2[2], (short)ul2[3],
               (short)ul2[4], (short)ul2[5], (short)ul2[6], (short)ul2[7]};
}

// ---------------------------------------------------------------------------
// Kernel 1 (v7): corr + stable top-4 via bf16x3 MFMA.
//  - 64-row chunks (LDS 15.4 KB) -> 8 blocks/CU co-resident.
//  - XOR-swizzled V-frag slots: slot = g ^ (row&3) (write and read).
//  - SPLIT=2: k-split, blockIdx.x = qc*2+half, each block scans 512 k,
//    writes partial sorted (val,idx) lists; merge kernel combines.
// Lane L: C col = q = L&15; rows k = base + (L>>4)*4 + reg.
// ---------------------------------------------------------------------------
template <int SPLIT, int PRESPLIT>
__global__ __launch_bounds__(256) void corr_topk_kernel(
    const float* __restrict__ query, const float* __restrict__ value,
    const ushort* __restrict__ vs, int* __restrict__ idx_out,
    float4* __restrict__ pval, int4* __restrict__ pidx) {
  __shared__ ushort hiL[64][40];  // 40-ushort rows; 4 frag slots + pad
  __shared__ ushort loL[64][40];
  __shared__ ushort lo2L[64][40];

  const int tid = threadIdx.x;
  const int nh = blockIdx.z;  // n*8+h
  const int n = nh >> 3, h = nh & 7;
  const int l = blockIdx.y;
  const int qc = (SPLIT == 2) ? ((int)blockIdx.x >> 1) : (int)blockIdx.x;
  const int half = (SPLIT == 2) ? ((int)blockIdx.x & 1) : 0;
  const int c0 = (SPLIT == 2) ? (half << 3) : 0;   // chunk base (64-row chunks)
  const int c1 = (SPLIT == 2) ? (c0 + 8) : 16;
  const int w = tid >> 6, L = tid & 63;
  const int qtile = (qc << 2) + w;     // 0..63
  const int r16 = L & 15, g = L >> 4;  // C: col=r16(q), row-group g

  // ---- Q fragments (persistent) ----
  bf16x8 qhi, qlo, qlo2;
  {
    const float* qp =
        query + (size_t)(n * LQ + (qtile << 4) + r16) * DM + h * DH + (g << 3);
    float qf[8];
    *(float4*)&qf[0] = *(const float4*)qp;
    *(float4*)&qf[4] = *(const float4*)(qp + 4);
    ushort uh[8], ul[8], ul2[8];
    #pragma unroll
    for (int j = 0; j < 8; ++j) {
      const float x = qf[j];
      const ushort h1 = bf16rn(x);
      const float r1 = x - bf16tof(h1);
      const ushort h2 = bf16rn(r1);
      const float r2 = r1 - bf16tof(h2);
      uh[j] = h1; ul[j] = h2; ul2[j] = bf16rn(r2);
    }
    qhi = (bf16x8){(short)uh[0], (short)uh[1], (short)uh[2], (short)uh[3],
                   (short)uh[4], (short)uh[5], (short)uh[6], (short)uh[7]};
    qlo = (bf16x8){(short)ul[0], (short)ul[1], (short)ul[2], (short)ul[3],
                   (short)ul[4], (short)ul[5], (short)ul[6], (short)ul[7]};
    qlo2 = (bf16x8){(short)ul2[0], (short)ul2[1], (short)ul2[2], (short)ul2[3],
                    (short)ul2[4], (short)ul2[5], (short)ul2[6], (short)ul2[7]};
  }

  float v0 = -INFINITY, v1 = -INFINITY, v2 = -INFINITY, v3 = -INFINITY;
  int i0 = 0, i1 = 0, i2 = 0, i3 = 0;

  // staging mapping: 64 rows x 32 ushorts per plane; thread -> (srow, slot)
  const int srow = tid >> 2, s = tid & 3;
  const int wslot = (s ^ (srow & 3)) << 3;  // swizzled ushort col
  const ushort* psbase =
      PRESPLIT ? vs + ((((size_t)((n * NL + l) * NH + h)) << 10)) * 32 : nullptr;
  const float* vbase = value + (size_t)(n * LIN + l * HWsp) * DM + h * DH;

  for (int c = c0; c < c1; ++c) {
    if (PRESPLIT) {
      const size_t off = ((size_t)((c << 6) + srow)) * 32 + (s << 3);
      *(bf16x8*)&hiL[srow][wslot] = *(const bf16x8*)(psbase + off);
      *(bf16x8*)&loL[srow][wslot] = *(const bf16x8*)(psbase + PSTRIDE + off);
      *(bf16x8*)&lo2L[srow][wslot] = *(const bf16x8*)(psbase + 2 * PSTRIDE + off);
    } else {
      const float* vp = vbase + (size_t)((c << 6) + srow) * DM + (s << 3);
      float xf[8];
      *(float4*)&xf[0] = *(const float4*)vp;
      *(float4*)&xf[4] = *(const float4*)(vp + 4);
      ushort uh[8], ul[8], ul2[8];
      #pragma unroll
      for (int j = 0; j < 8; ++j) {
        const float x = xf[j];
        const ushort h1 = bf16rn(x);
        const float r1 = x - bf16tof(h1);
        const ushort h2 = bf16rn(r1);
        const float r2 = r1 - bf16tof(h2);
        uh[j] = h1; ul[j] = h2; ul2[j] = bf16rn(r2);
      }
      *(bf16x8*)&hiL[srow][wslot] =
          (bf16x8){(short)uh[0], (short)uh[1], (short)uh[2], (short)uh[3],
                   (short)uh[4], (short)uh[5], (short)uh[6], (short)uh[7]};
      *(bf16x8*)&loL[srow][wslot] =
          (bf16x8){(short)ul[0], (short)ul[1], (short)ul[2], (short)ul[3],
                   (short)ul[4], (short)ul[5], (short)ul[6], (short)ul[7]};
      *(bf16x8*)&lo2L[srow][wslot] =
          (bf16x8){(short)ul2[0], (short)ul2[1], (short)ul2[2], (short)ul2[3],
                   (short)ul2[4], (short)ul2[5], (short)ul2[6], (short)ul2[7]};
    }
    __syncthreads();

    #pragma unroll
    for (int t = 0; t < 4; ++t) {
      const int row = (t << 4) + r16;
      const int rslot = (g ^ (row & 3)) << 3;  // swizzled read col
      const bf16x8 ahi = *(const bf16x8*)&hiL[row][rslot];
      const bf16x8 alo = *(const bf16x8*)&loL[row][rslot];
      const bf16x8 alo2 = *(const bf16x8*)&lo2L[row][rslot];
      f32x4 acc = {0.f, 0.f, 0.f, 0.f};
      // smallest-first accumulation (validated R5/R6 ordering)
      acc = __builtin_amdgcn_mfma_f32_16x16x32_bf16(alo2, qhi, acc, 0, 0, 0);
      acc = __builtin_amdgcn_mfma_f32_16x16x32_bf16(ahi, qlo2, acc, 0, 0, 0);
      acc = __builtin_amdgcn_mfma_f32_16x16x32_bf16(alo, qlo, acc, 0, 0, 0);
      acc = __builtin_amdgcn_mfma_f32_16x16x32_bf16(alo, qhi, acc, 0, 0, 0);
      acc = __builtin_amdgcn_mfma_f32_16x16x32_bf16(ahi, qlo, acc, 0, 0, 0);
      acc = __builtin_amdgcn_mfma_f32_16x16x32_bf16(ahi, qhi, acc, 0, 0, 0);
      const int kb = (c << 6) + (t << 4) + (g << 2);
      INSERT4(acc[0], kb + 0);
      INSERT4(acc[1], kb + 1);
      INSERT4(acc[2], kb + 2);
      INSERT4(acc[3], kb + 3);
    }
    __syncthreads();
  }

  // ---- merge the 4 row-groups of this q-column ----
  #pragma unroll
  for (int m = 16; m < 64; m <<= 1) {
    const float b0 = __shfl_xor(v0, m);
    const float b1 = __shfl_xor(v1, m);
    const float b2 = __shfl_xor(v2, m);
    const float b3 = __shfl_xor(v3, m);
    const int j0 = __shfl_xor(i0, m);
    const int j1 = __shfl_xor(i1, m);
    const int j2 = __shfl_xor(i2, m);
    const int j3 = __shfl_xor(i3, m);
    LMAX(v0, i0, b3, j3);
    LMAX(v1, i1, b2, j2);
    LMAX(v2, i2, b1, j1);
    LMAX(v3, i3, b0, j0);
    CEX(v0, i0, v2, i2);
    CEX(v1, i1, v3, i3);
    CEX(v0, i0, v1, i1);
    CEX(v2, i2, v3, i3);
  }

  if (L < 16) {
    const int q = (qtile << 4) + L;
    const size_t gi = (((size_t)nh * NL + l) << 10) + q;
    if (SPLIT == 2) {
      pval[gi * 2 + half] = make_float4(v0, v1, v2, v3);
      pidx[gi * 2 + half] = make_int4(i0, i1, i2, i3);
    } else {
      ((int4*)idx_out)[gi] = make_int4(i0, i1, i2, i3);
    }
  }
}

// ---------------------------------------------------------------------------
// Kernel 1b: merge the two k-half partial top-4 lists per group (R4-validated).
// ---------------------------------------------------------------------------
__global__ __launch_bounds__(256) void merge_topk_kernel(
    const float4* __restrict__ pval, const int4* __restrict__ pidx,
    int* __restrict__ idx_out) {
  const int t = blockIdx.x * 256 + threadIdx.x;  // < NGRP
  const float4 av = pval[t * 2 + 0];
  const int4 ai = pidx[t * 2 + 0];
  const float4 bv = pval[t * 2 + 1];
  const int4 bi = pidx[t * 2 + 1];
  float w0 = av.x, w1 = av.y, w2 = av.z, w3 = av.w;
  int m0 = ai.x, m1 = ai.y, m2 = ai.z, m3 = ai.w;
  LMAX(w0, m0, bv.w, bi.w);
  LMAX(w1, m1, bv.z, bi.z);
  LMAX(w2, m2, bv.y, bi.y);
  LMAX(w3, m3, bv.x, bi.x);
  CEX(w0, m0, w2, m2);
  CEX(w1, m1, w3, m3);
  CEX(w0, m0, w1, m1);
  CEX(w2, m2, w3, m3);
  ((int4*)idx_out)[t] = make_int4(m0, m1, m2, m3);
}

// ---------------------------------------------------------------------------
// Kernel 2: loc output. res=clip(idx+delta,0,961); loc=(res>>5, res&31)/32.
// ---------------------------------------------------------------------------
__global__ __launch_bounds__(256) void loc_kernel(const int* __restrict__ idx_buf,
                                                  float* __restrict__ loc) {
  const int t = blockIdx.x * 256 + threadIdx.x;  // < 2359296
  const int k = t % 36;
  int rest = t / 36;
  const int l = rest & 3; rest >>= 2;
  const int h = rest & 7; rest >>= 3;
  const int q = rest & 1023;
  const int n = rest >> 10;
  const int p = k & 3, dd = k >> 2;  // delta-major: k = dd*4 + p
  const int idx = idx_buf[(((((n << 3) + h) * NL + l) << 10) + q) * 4 + p];
  const int delta = ((dd / 3) - 1) * 32 + (dd % 3) - 1;
  int res = idx + delta;
  res = min(max(res, 0), 961);
  const int W = res >> 5, H = res & 31;
  ((float2*)loc)[t] = make_float2((float)W * 0.03125f, (float)H * 0.03125f);
}

// ---------------------------------------------------------------------------
// Kernel 3 (v2): gather+average, wave-per-(n,q,h,l) -> wave-uniform branches.
// Interior p (H0 in [2,30], W0 in [2,28]): 9 cells x 4 corners == 16-row tent
// (1,2,2,1) x (1,2,2,1) around idx_T = (H0<<5)+W0 (transposed space).
// Boundary p: exact 36-unit (cell,corner) enumeration with clamp+gates.
// All scaled by 1/576 at the end (matches reference weighting exactly).
// Grid: (n*1024+q)*8+h blocks x 256 threads (4 waves = 4 levels).
// ---------------------------------------------------------------------------
__global__ __launch_bounds__(256) void gather_kernel(
    const float* __restrict__ value, const int* __restrict__ idx_buf,
    float* __restrict__ acc_out) {
  __shared__ float4 red[NL][8];
  const int bh = blockIdx.x;  // (n*1024+q)*8 + h
  const int h = bh & 7;
  const int nq = bh >> 3;
  const int n = nq >> 10, q = nq & 1023;
  const int tid = threadIdx.x;
  const int l = tid >> 6;  // wave = level
  const int L = tid & 63;
  const int cp = L >> 3, d4 = L & 7;

  const int4 id4 =
      ((const int4*)idx_buf)[((((size_t)((n << 3) + h)) * NL + l) << 10) + q];
  const float4* vb4 =
      (const float4*)(value + (size_t)(n * LIN + l * HWsp) * DM + h * DH) + d4;

  float4 a = make_float4(0.f, 0.f, 0.f, 0.f);
  #pragma unroll
  for (int p = 0; p < 4; ++p) {
    const int idx = (p == 0) ? id4.x : (p == 1) ? id4.y : (p == 2) ? id4.z : id4.w;
    const int H0 = idx & 31, W0 = idx >> 5;
    if (H0 >= 2 && H0 <= 30 && W0 >= 2 && W0 <= 28) {
      // interior: 16 cells, lane handles cells c0i=2cp (ax0 in {0,2}), c0i+1
      const int idxT = (H0 << 5) + W0;
      const int c0i = cp << 1;
      const int ax0 = c0i & 3, ay = c0i >> 2;
      const int r0 = idxT + (ax0 - 2) * 32 + (ay - 2);
      const float wy = (ay == 1 || ay == 2) ? 2.f : 1.f;
      const float f0 = ((ax0 == 2) ? 2.f : 1.f) * wy;   // ax0 in {0,2}
      const float f1 = ((ax0 + 1 == 1) ? 2.f : 1.f) * wy;  // ax0+1 in {1,3}
      const float4 va = vb4[(size_t)r0 * 64];
      const float4 vbb = vb4[(size_t)(r0 + 32) * 64];
      a.x += f0 * va.x + f1 * vbb.x;
      a.y += f0 * va.y + f1 * vbb.y;
      a.z += f0 * va.z + f1 * vbb.z;
      a.w += f0 * va.w + f1 * vbb.w;
    } else {
      // boundary: enumerate 36 (cell,corner) units, 8 units per iteration
      #pragma unroll
      for (int it = 0; it < 5; ++it) {
        const int u = cp + (it << 3);
        const int cell = u >> 2, corner = u & 3;
        const int dy = (cell >= 3) + (cell >= 6) - 1;
        const int dx = cell - (dy + 1) * 3 - 1;
        int res = idx + dy * 32 + dx;
        res = min(max(res, 0), 961);
        const int W = res >> 5, H = res & 31;
        const int cw = corner & 1, ch = corner >> 1;
        const bool ok = (u < 36) && (W >= cw) && (H >= ch);
        const int row = ok ? (((H - ch) << 5) + (W - cw)) : 0;
        const float wgt = ok ? 1.f : 0.f;
        const float4 v = vb4[(size_t)row * 64];
        a.x += wgt * v.x;
        a.y += wgt * v.y;
        a.z += wgt * v.z;
        a.w += wgt * v.w;
      }
    }
  }

  // reduce over the 8 cp-classes (lanes sharing d4)
  #pragma unroll
  for (int m = 8; m < 64; m <<= 1) {
    a.x += __shfl_xor(a.x, m);
    a.y += __shfl_xor(a.y, m);
    a.z += __shfl_xor(a.z, m);
    a.w += __shfl_xor(a.w, m);
  }
  if (L < 8) red[l][L] = a;
  __syncthreads();
  if (tid < 8) {
    const float4 s0 = red[0][tid], s1 = red[1][tid], s2 = red[2][tid],
                 s3 = red[3][tid];
    float4 o;
    o.x = (s0.x + s1.x + s2.x + s3.x) * (1.0f / 576.0f);
    o.y = (s0.y + s1.y + s2.y + s3.y) * (1.0f / 576.0f);
    o.z = (s0.z + s1.z + s2.z + s3.z) * (1.0f / 576.0f);
    o.w = (s0.w + s1.w + s2.w + s3.w) * (1.0f / 576.0f);
    ((float4*)(acc_out + (size_t)nq * DM + h * DH))[tid] = o;
  }
}

// ---------------------------------------------------------------------------
// Kernel 4: out = acc @ W^T + b.  256 blocks x 256 threads, 8 q-rows/block.
// ---------------------------------------------------------------------------
__global__ __launch_bounds__(256) void proj_kernel(
    const float* __restrict__ acc_in, const float* __restrict__ W,
    const float* __restrict__ bias, float* __restrict__ out) {
  __shared__ float la[8][256];
  const int qb = blockIdx.x << 3;
  const int tid = threadIdx.x;
  for (int i = tid; i < 8 * 256; i += 256)
    la[i >> 8][i & 255] = acc_in[((size_t)qb << 8) + i];
  __syncthreads();
  const float* wrow = W + (size_t)tid * 256;
  float s0 = 0.f, s1 = 0.f, s2 = 0.f, s3 = 0.f, s4 = 0.f, s5 = 0.f, s6 = 0.f, s7 = 0.f;
  for (int c0 = 0; c0 < 256; c0 += 4) {
    const float4 wv = *(const float4*)(wrow + c0);
    #define PROJ_STEP(qi, sreg)                                   \
      {                                                           \
        const float4 av = *(const float4*)&la[qi][c0];            \
        sreg = fmaf(wv.x, av.x, sreg);                            \
        sreg = fmaf(wv.y, av.y, sreg);                            \
        sreg = fmaf(wv.z, av.z, sreg);                            \
        sreg = fmaf(wv.w, av.w, sreg);                            \
      }
    PROJ_STEP(0, s0) PROJ_STEP(1, s1) PROJ_STEP(2, s2) PROJ_STEP(3, s3)
    PROJ_STEP(4, s4) PROJ_STEP(5, s5) PROJ_STEP(6, s6) PROJ_STEP(7, s7)
    #undef PROJ_STEP
  }
  const float bj = bias[tid];
  out[(size_t)(qb + 0) * 256 + tid] = s0 + bj;
  out[(size_t)(qb + 1) * 256 + tid] = s1 + bj;
  out[(size_t)(qb + 2) * 256 + tid] = s2 + bj;
  out[(size_t)(qb + 3) * 256 + tid] = s3 + bj;
  out[(size_t)(qb + 4) * 256 + tid] = s4 + bj;
  out[(size_t)(qb + 5) * 256 + tid] = s5 + bj;
  out[(size_t)(qb + 6) * 256 + tid] = s6 + bj;
  out[(size_t)(qb + 7) * 256 + tid] = s7 + bj;
}

// ---------------------------------------------------------------------------
extern "C" void kernel_launch(void* const* d_in, const int* in_sizes, int n_in,
                              void* d_out, int out_size, void* d_ws, size_t ws_size,
                              hipStream_t stream) {
  (void)in_sizes; (void)n_in; (void)out_size;
  const float* query = (const float*)d_in[0];
  const float* value = (const float*)d_in[2];
  const float* opw = (const float*)d_in[5];
  const float* opb = (const float*)d_in[6];

  float* out = (float*)d_out;               // [2,1024,256]
  float* loc = out + (size_t)BB * LQ * DM;  // [2,1024,8,4,36,2]

  const size_t SPLITB = 3 * PSTRIDE * sizeof(ushort);               // 12.58 MB
  const size_t PARTB = (size_t)NGRP * 2 * 16;                       // 2 MB each
  const size_t IDXB = (size_t)NGRP * 4 * sizeof(int);               // 1 MB
  const size_t ACCB = (size_t)BB * LQ * DM * sizeof(float);         // 2 MB

  if (ws_size >= SPLITB + 2 * PARTB + IDXB + ACCB) {
    // full path: presplit + k-split
    ushort* vsb = (ushort*)d_ws;
    float4* pval = (float4*)((char*)d_ws + SPLITB);
    int4* pidx = (int4*)((char*)d_ws + SPLITB + PARTB);
    int* idx_buf = (int*)((char*)d_ws + SPLITB + 2 * PARTB);
    float* acc_buf = (float*)((char*)d_ws + SPLITB + 2 * PARTB + IDXB);

    vsplit_kernel<<<dim3(1024), 256, 0, stream>>>(value, vsb);
    corr_topk_kernel<2, 1><<<dim3(32, NL, BB * NH), 256, 0, stream>>>(
        query, value, vsb, idx_buf, pval, pidx);
    merge_topk_kernel<<<dim3(NGRP / 256), 256, 0, stream>>>(pval, pidx, idx_buf);
    loc_kernel<<<dim3((BB * LQ * NH * NL * K9) / 256), 256, 0, stream>>>(idx_buf, loc);
    gather_kernel<<<dim3(BB * LQ * NH), 256, 0, stream>>>(value, idx_buf, acc_buf);
    proj_kernel<<<dim3(BB * LQ / 8), 256, 0, stream>>>(acc_buf, opw, opb, out);
  } else if (ws_size >= 2 * PARTB + IDXB + ACCB) {
    // k-split, in-kernel conversion
    float4* pval = (float4*)d_ws;
    int4* pidx = (int4*)((char*)d_ws + PARTB);
    int* idx_buf = (int*)((char*)d_ws + 2 * PARTB);
    float* acc_buf = (float*)((char*)d_ws + 2 * PARTB + IDXB);

    corr_topk_kernel<2, 0><<<dim3(32, NL, BB * NH), 256, 0, stream>>>(
        query, value, (const ushort*)nullptr, idx_buf, pval, pidx);
    merge_topk_kernel<<<dim3(NGRP / 256), 256, 0, stream>>>(pval, pidx, idx_buf);
    loc_kernel<<<dim3((BB * LQ * NH * NL * K9) / 256), 256, 0, stream>>>(idx_buf, loc);
    gather_kernel<<<dim3(BB * LQ * NH), 256, 0, stream>>>(value, idx_buf, acc_buf);
    proj_kernel<<<dim3(BB * LQ / 8), 256, 0, stream>>>(acc_buf, opw, opb, out);
  } else {
    // minimal: single-pass, in-kernel conversion
    int* idx_buf = (int*)d_ws;
    float* acc_buf = (float*)((char*)d_ws + IDXB);

    corr_topk_kernel<1, 0><<<dim3(16, NL, BB * NH), 256, 0, stream>>>(
        query, value, (const ushort*)nullptr, idx_buf, (float4*)nullptr,
        (int4*)nullptr);
    loc_kernel<<<dim3((BB * LQ * NH * NL * K9) / 256), 256, 0, stream>>>(idx_buf, loc);
    gather_kernel<<<dim3(BB * LQ * NH), 256, 0, stream>>>(value, idx_buf, acc_buf);
    proj_kernel<<<dim3(BB * LQ / 8), 256, 0, stream>>>(acc_buf, opw, opb, out);
  }
}